// Round 10
// baseline (415.971 us; speedup 1.0000x reference)
//
#include <hip/hip_runtime.h>
#include <hip/hip_bf16.h>

#define IN_F   4096
#define OUT_F  11008
#define NHIGH  2752
#define NLOW   8256
#define M_TOT  4096   // B*S = 2*2048

typedef __attribute__((ext_vector_type(8))) short bf16x8;
typedef __attribute__((ext_vector_type(4))) float f32x4;
typedef __attribute__((ext_vector_type(4))) float f32x4v;

__device__ __forceinline__ short f2bf(float f) {
    union { float f; unsigned u; } v; v.f = f;
    unsigned r = (v.u + 0x7fffu + ((v.u >> 16) & 1u)) >> 16;
    return (short)(r & 0xffffu);
}

__device__ __forceinline__ void async16(const void* g, const void* l) {
    __builtin_amdgcn_global_load_lds(
        (const __attribute__((address_space(1))) unsigned int*)g,
        (__attribute__((address_space(3))) unsigned int*)l, 16, 0, 0);
}

// ---------------- kernel 0: forward permutation fwd[cinv[n]] = n ----------------
__global__ void fwd_perm_kernel(const int* __restrict__ cinv, int* __restrict__ fwd) {
    int n = blockIdx.x * blockDim.x + threadIdx.x;
    if (n < OUT_F) fwd[cinv[n]] = n;
}

// ---------------- kernel 1: x f32 -> bf16 (nt loads: read-once) ----------------
__global__ void cvt_x_kernel(const float* __restrict__ x, short* __restrict__ xb) {
    const int nv = (M_TOT * IN_F) / 8;
    for (int i = blockIdx.x * blockDim.x + threadIdx.x; i < nv;
         i += gridDim.x * blockDim.x) {
        const f32x4v* p = (const f32x4v*)(x + (long)i * 8);
        f32x4v a = __builtin_nontemporal_load(p);
        f32x4v b = __builtin_nontemporal_load(p + 1);
        bf16x8 o;
        o[0] = f2bf(a[0]); o[1] = f2bf(a[1]); o[2] = f2bf(a[2]); o[3] = f2bf(a[3]);
        o[4] = f2bf(b[0]); o[5] = f2bf(b[1]); o[6] = f2bf(b[2]); o[7] = f2bf(b[3]);
        *(bf16x8*)(xb + (long)i * 8) = o;
    }
}

// ---------------- kernel 2: dequant (source-major) + scatter-permute ----------------
__global__ void dequant_kernel(const int* __restrict__ hw, const float* __restrict__ hs,
                               const int* __restrict__ lw, const float* __restrict__ s1,
                               const float* __restrict__ s2, const float* __restrict__ zp,
                               const int* __restrict__ fwd,
                               short* __restrict__ wt) {
    __shared__ short tile[64 * 66];
    const int t  = threadIdx.x;
    const int c0 = blockIdx.x * 64;
    const int k0 = blockIdx.y * 64;
    const int cl = t & 63;
    const int w  = t >> 6;

    if (c0 < NHIGH) {
        const int ci = c0 + cl;
        #pragma unroll
        for (int i = 0; i < 16; ++i) {
            const int kl = w + 4 * i;
            const int k  = k0 + kl;
            int   q   = __builtin_nontemporal_load(&hw[(long)k * NHIGH + ci]);
            float val = (float)q * hs[(k >> 7) * NHIGH + ci];
            tile[cl * 66 + kl] = f2bf(val);
        }
    } else {
        const int ci = c0 - NHIGH + cl;
        const float s2v = s2[ci];
        #pragma unroll
        for (int i = 0; i < 16; ++i) {
            const int kl = w + 4 * i;
            const int k  = k0 + kl;
            int   q   = __builtin_nontemporal_load(&lw[(long)k * NLOW + ci]);
            float val = ((float)q - zp[k]) * s1[k] * s2v;
            tile[cl * 66 + kl] = f2bf(val);
        }
    }
    __syncthreads();
    const int oc = t >> 2;
    const int kq = (t & 3) * 16;
    bf16x8 o0, o1;
    #pragma unroll
    for (int j = 0; j < 8; ++j) {
        o0[j] = tile[oc * 66 + kq + j];
        o1[j] = tile[oc * 66 + kq + 8 + j];
    }
    const int ndst = fwd[c0 + oc];
    short* dst = wt + (long)ndst * IN_F + k0 + kq;
    *(bf16x8*)dst       = o0;
    *(bf16x8*)(dst + 8) = o1;
}

// ---------------- kernel 3: 128x128 GEMM, 64KB LDS -> 2 blocks/CU ----------------
// 4 waves (2x2) of 64x64. R9 single-sync body. Cross-block pipe overlap test:
// two independent blocks per CU let one block's LDS-read burst fill the other
// block's MFMA pipe gaps (m114 mechanism).
#define BM 128
#define BN 128
#define BK 64
#define KT (IN_F / BK)        // 64
#define NTIL (OUT_F / BN)     // 86
#define MTIL (M_TOT / BM)     // 32
#define NWG3 (NTIL * MTIL)    // 2752 (= 8 * 344)

#define BAR()    __builtin_amdgcn_s_barrier()
#define VMC0()   asm volatile("s_waitcnt vmcnt(0)" ::: "memory")

__global__ __launch_bounds__(256, 2) void gemm_kernel(
    const short* __restrict__ A,    // [M_TOT][IN_F] bf16
    const short* __restrict__ Bt,   // [OUT_F][IN_F] bf16
    const float* __restrict__ bias,
    float* __restrict__ C) {
    __shared__ __align__(16) short lds_s[32768];   // 64 KiB: 2 buf x (A 16K | B 16K)
    char* const lds = (char*)lds_s;

    const int t    = threadIdx.x;
    const int lane = t & 63;
    const int w    = t >> 6;      // 0..3
    const int wr   = w >> 1;      // 0..1  (M)
    const int wc   = w & 1;       // 0..1  (N)

    // XCD-bijective swizzle (2752 % 8 == 0) + supertile GSUP=8 (R3-proven at 128²)
    const int swz   = (blockIdx.x % 8) * (NWG3 / 8) + blockIdx.x / 8;
    const int sr    = swz / (8 * NTIL);          // 0..3
    const int in_sr = swz % (8 * NTIL);
    const int nb    = in_sr / 8;                 // 0..85
    const int mb    = sr * 8 + (in_sr & 7);      // 0..31
    const int m0    = mb * BM;
    const int n0    = nb * BN;

    // staging: wave w covers 32 rows of A and 32 rows of B (4 instr each, 8 rows/instr)
    // lane l -> row +(l>>3), source col-byte pre-swizzled ((l&7)^(l>>3))*16
    const int srow = w * 32 + (lane >> 3);
    const int scb  = ((lane & 7) ^ (lane >> 3)) * 16;
    const char* gA0 = (const char*)A  + (long)(m0 + srow) * (IN_F * 2) + scb;
    const char* gB0 = (const char*)Bt + (long)(n0 + srow) * (IN_F * 2) + scb;

    // ds_read lane bases (rows are 128 B, same XOR swizzle as R9)
    const int rl  = (lane & 15) * 128;
    const int kb0 = ((lane >> 4) * 16) ^ ((lane & 7) << 4);
    const int kb1 = kb0 ^ 64;

// stage one 32-KB tile (A 16K + B 16K) into buf: 8 async16/thread.
// A region: buf*32768 + [0,16384); B region: buf*32768 + 16384.
#define STAGE_TILE(buf, ktile) do {                                              \
        const char* _ga = gA0 + (ktile) * 128;                                   \
        const char* _gb = gB0 + (ktile) * 128;                                   \
        char* _la = lds + (buf) * 32768 +         w * 4096 + (lane) * 16;        \
        char* _lb = lds + (buf) * 32768 + 16384 + w * 4096 + (lane) * 16;        \
        _Pragma("unroll")                                                        \
        for (int _j = 0; _j < 4; ++_j) {                                         \
            async16(_ga + (long)(_j * 8) * (IN_F * 2), _la + _j * 1024);         \
            async16(_gb + (long)(_j * 8) * (IN_F * 2), _lb + _j * 1024);         \
        }                                                                        \
    } while (0)

    f32x4 acc[4][4];
    #pragma unroll
    for (int i = 0; i < 4; ++i)
        #pragma unroll
        for (int j = 0; j < 4; ++j)
            acc[i][j] = (f32x4){0.f, 0.f, 0.f, 0.f};

    bf16x8 af[4][2], bfm[4][2];

#define RD_ALL(buf) do {                                                         \
        char* _pa = lds + (buf) * 32768 +         (wr * 64) * 128 + rl;          \
        char* _pb = lds + (buf) * 32768 + 16384 + (wc * 64) * 128 + rl;          \
        _Pragma("unroll")                                                        \
        for (int _i = 0; _i < 4; ++_i) {                                         \
            af[_i][0]  = *(const bf16x8*)(_pa + _i * 2048 + kb0);                \
            af[_i][1]  = *(const bf16x8*)(_pa + _i * 2048 + kb1);                \
            bfm[_i][0] = *(const bf16x8*)(_pb + _i * 2048 + kb0);                \
            bfm[_i][1] = *(const bf16x8*)(_pb + _i * 2048 + kb1);                \
        }                                                                        \
    } while (0)

// one K-tile: 16 reads -> stage next tile into buf^1 -> 32 MFMA -> VMC0+BAR
#define TILE_BODY(buf, ktn) do {                                                 \
        RD_ALL(buf);                                                             \
        STAGE_TILE((buf) ^ 1, ktn);                                              \
        __builtin_amdgcn_s_setprio(1);                                           \
        _Pragma("unroll")                                                        \
        for (int _m = 0; _m < 4; ++_m)                                           \
        _Pragma("unroll")                                                        \
        for (int _n = 0; _n < 4; ++_n) {                                         \
            acc[_m][_n] = __builtin_amdgcn_mfma_f32_16x16x32_bf16(               \
                af[_m][0], bfm[_n][0], acc[_m][_n], 0, 0, 0);                    \
            acc[_m][_n] = __builtin_amdgcn_mfma_f32_16x16x32_bf16(               \
                af[_m][1], bfm[_n][1], acc[_m][_n], 0, 0, 0);                    \
        }                                                                        \
        __builtin_amdgcn_s_setprio(0);                                           \
        VMC0(); BAR();                                                           \
    } while (0)

    // prologue: stage tile 0 into buf0
    STAGE_TILE(0, 0);
    VMC0();
    BAR();

    #pragma unroll 1
    for (int it = 0; it < KT / 2; ++it) {
        const int kt1 = 2 * it + 1;                               // < KT always
        const int kt2 = (2 * it + 2 < KT) ? 2 * it + 2 : KT - 1;  // clamp: benign restage
        TILE_BODY(0, kt1);
        TILE_BODY(1, kt2);
    }

    // epilogue: nt stores. row = m0+wr*64+mi*16+(lane>>4)*4+r, col = n0+wc*64+ni*16+(lane&15)
    const int er = m0 + wr * 64 + (lane >> 4) * 4;
    const int ec = n0 + wc * 64 + (lane & 15);
    #pragma unroll
    for (int ni = 0; ni < 4; ++ni) {
        const float bv = bias[ec + ni * 16];
        #pragma unroll
        for (int mi = 0; mi < 4; ++mi) {
            #pragma unroll
            for (int r = 0; r < 4; ++r) {
                __builtin_nontemporal_store(
                    acc[mi][ni][r] + bv,
                    &C[(long)(er + mi * 16 + r) * OUT_F + ec + ni * 16]);
            }
        }
    }
}

extern "C" void kernel_launch(void* const* d_in, const int* in_sizes, int n_in,
                              void* d_out, int out_size, void* d_ws, size_t ws_size,
                              hipStream_t stream) {
    const float* x    = (const float*)d_in[0];
    const int*   hw   = (const int*)d_in[1];
    const float* hs   = (const float*)d_in[2];
    const int*   lw   = (const int*)d_in[3];
    const float* s1   = (const float*)d_in[4];
    const float* s2   = (const float*)d_in[5];
    const float* zp   = (const float*)d_in[6];
    const int*   cinv = (const int*)d_in[7];
    const float* bias = (const float*)d_in[8];
    float*       out  = (float*)d_out;

    short* wt  = (short*)d_ws;                                     // 90,177,536 B
    short* xb  = (short*)((char*)d_ws + (size_t)OUT_F * IN_F * 2); // +33,554,432 B
    int*   fwd = (int*)((char*)d_ws + (size_t)OUT_F * IN_F * 2
                                    + (size_t)M_TOT * IN_F * 2);   // +44,032 B

    fwd_perm_kernel<<<(OUT_F + 255) / 256, 256, 0, stream>>>(cinv, fwd);
    cvt_x_kernel<<<2048, 256, 0, stream>>>(x, xb);
    dequant_kernel<<<dim3(OUT_F / 64, IN_F / 64), 256, 0, stream>>>(
        hw, hs, lw, s1, s2, zp, fwd, wt);
    gemm_kernel<<<NWG3, 256, 0, stream>>>(xb, wt, bias, out);
}